// Round 11
// baseline (3967.221 us; speedup 1.0000x reference)
//
#include <hip/hip_runtime.h>

// LSTM_36807869726767 — round 15: round 14 + __launch_bounds__(256,1).
// Round-14 post-mortem: −21% BUT VGPR_Count stayed 68 -> the ha[32]/ea[16]
// register burst NEVER materialized (launch_bounds(256) without min-waves
// let the allocator target ~64 VGPR; burst rolled back to a narrow window).
// The win came from e-pipeline + s_sleep(1). The h-load latency term is
// still partially unpaid (~8K cyc/step unaccounted = serialized L3 trips).
// This round, ONE variable: __launch_bounds__(256, 1) -> up to 512 VGPR at
// our actual occupancy (1 wave/SIMD, unchanged). Burst becomes real: 48
// loads in flight, first h-MFMA pays ONE L3 latency.
// Tell: VGPR_Count >= 200. If VGPR rises but dur flat -> latency theory
// falsified, residual is barrier chain.
// B=64, S=512, E=512, H=1024, NCLS=10, PAD=0. All float I/O f32.

typedef _Float16 f16;
typedef __attribute__((ext_vector_type(8))) _Float16 f16x8;
typedef __attribute__((ext_vector_type(4))) _Float16 f16x4;
typedef __attribute__((ext_vector_type(4))) float f32x4;

#define Bn 64
#define Sn 512
#define En 512
#define Hn 1024

__device__ __forceinline__ float fsig(float x) {
    return __builtin_amdgcn_rcpf(1.f + __expf(-x));
}
__device__ __forceinline__ float ftanh(float x) {
    return 2.f * __builtin_amdgcn_rcpf(1.f + __expf(-2.f * x)) - 1.f;
}

// ------------------------------------------------- gather e -> f16 [t][b][k]
__global__ __launch_bounds__(256) void gather_e_k(
    const int* __restrict__ x, const float* __restrict__ emb,
    f16* __restrict__ e16)
{
    size_t g = (size_t)blockIdx.x * 256 + threadIdx.x;
    int row = (int)(g >> 6);          // t*64 + b
    int ko  = (int)(g & 63) * 8;
    int t = row >> 6, b = row & 63;
    int tok = x[b * Sn + t];
    float4 a  = *(const float4*)&emb[(size_t)tok * En + ko];
    float4 a2 = *(const float4*)&emb[(size_t)tok * En + ko + 4];
    float v[8] = {a.x, a.y, a.z, a.w, a2.x, a2.y, a2.z, a2.w};
    f16x8 h;
    #pragma unroll
    for (int i = 0; i < 8; ++i) h[i] = (f16)v[i];
    *(f16x8*)&e16[(size_t)row * En + ko] = h;
}

// ------------------------------------------------------------- Wa f32 -> f16
__global__ __launch_bounds__(256) void split_wa_k(
    const float* __restrict__ Wa, f16* __restrict__ hi)
{
    size_t g = ((size_t)blockIdx.x * 256 + threadIdx.x) * 8;
    float4 a = *(const float4*)&Wa[g];
    float4 b = *(const float4*)&Wa[g + 4];
    float v[8] = {a.x, a.y, a.z, a.w, b.x, b.y, b.z, b.w};
    f16x8 h;
    #pragma unroll
    for (int i = 0; i < 8; ++i) h[i] = (f16)v[i];
    *(f16x8*)&hi[g] = h;
}

// ------------------------------------------- persistent LSTM recurrence
// 256 blocks x 256 thr (1 wave/SIMD, all CUs). Block bk owns h-dims
// d0=4*bk..d0+3 (16 gate rows). Wave w = 16 batch rows. h state: write-once
// slots h16[slot][b][k] f16; slot t = state entering step t; slot 0 zeroed;
// step t writes slot t+1 via relaxed agent-scope u32 stores (two f16 packed;
// write-through to coherence point; readers use normal cached loads of
// write-once lines -> no stale data, no fences needed).
// Barrier: round-8 block-level (tid0 polls root, __syncthreads, tid0 arrive).
__global__ __launch_bounds__(256, 1) void lstm_persist_k(
    const f16* __restrict__ e16,      // [512*64][512]
    const float* __restrict__ Wg,     // [4096][1536] f32
    const float* __restrict__ bg,     // [4096]
    f16* __restrict__ h16,            // [513][64][1024] f16
    unsigned* __restrict__ bar)       // [16*32] group counters + [512] root
{
    // k-major [kchunk][16 rows][8]: zero pad, conflict-free ds_read_b128
    __shared__ f16 Wse[64 * 16 * 8];    // 16 KB (e-part, k=0..511)
    __shared__ f16 Wsh[128 * 16 * 8];   // 32 KB (h-part, k=512..1535)

    const int tid = threadIdx.x;
    const int bk  = blockIdx.x;     // 0..255
    const int d0  = bk * 4;

    // ---- one-time: stage 16 weight rows (f32 -> f16), k-major
    {
        int n = tid >> 4, l16 = tid & 15;
        int j = (n >> 2) * 1024 + d0 + (n & 3);
        const float* src = Wg + (size_t)j * 1536;
        for (int k = l16 * 4; k < 1536; k += 64) {
            float4 v = *(const float4*)&src[k];
            float vv[4] = {v.x, v.y, v.z, v.w};
            #pragma unroll
            for (int i = 0; i < 4; ++i) {
                int kk = k + i;
                f16 hv = (f16)vv[i];
                if (kk < 512) {
                    Wse[((kk >> 3) * 16 + n) * 8 + (kk & 7)] = hv;
                } else {
                    int kh = kk - 512;
                    Wsh[((kh >> 3) * 16 + n) * 8 + (kh & 7)] = hv;
                }
            }
        }
    }
    __syncthreads();

    const int lane = tid & 63;
    const int w    = tid >> 6;
    const int cl   = lane & 15;
    const int q    = lane >> 4;
    const int b    = w * 16 + cl;
    const int ko   = q * 8;
    const int co   = cl & 3;
    const int jcol = (cl >> 2) * 1024 + d0 + (cl & 3);
    const float bgv = bg[jcol];

    const int wbase = (q * 16 + cl) * 8;   // lane base into k-major LDS
    const f16* Wse_r = &Wse[wbase];
    const f16* Wsh_r = &Wsh[wbase];

    unsigned* grp  = &bar[(bk >> 4) * 32];
    unsigned* root = &bar[512];

    float cst[4] = {0.f, 0.f, 0.f, 0.f};
    int bail = 0;

    // ---- e software pipeline: prime ea with step 0's fragments
    f16x8 ea[16];
    {
        const f16* Ae0 = e16 + (size_t)b * En + ko;
        #pragma unroll
        for (int ks = 0; ks < 16; ++ks)
            ea[ks] = *(const f16x8*)&Ae0[ks * 32];
    }

    for (int t = 0; t < Sn; ++t) {
        // ---- e-part MFMAs from registers loaded one step ago
        f32x4 accE = {bgv, bgv, bgv, bgv};   // bias folded in
        #pragma unroll
        for (int ks = 0; ks < 16; ++ks) {
            f16x8 bb = *(const f16x8*)&Wse_r[ks * 512];
            accE = __builtin_amdgcn_mfma_f32_16x16x32_f16(ea[ks], bb, accE, 0, 0, 0);
        }

        // ---- wait for step t-1 (root >= 16*t); relaxed spin, no acquire
        if (tid == 0 && t > 0 && !bail) {
            unsigned tgt = 16u * (unsigned)t;
            long spins = 0;
            while (__hip_atomic_load(root, __ATOMIC_RELAXED,
                                     __HIP_MEMORY_SCOPE_AGENT) < tgt) {
                __builtin_amdgcn_s_sleep(1);
                if (++spins > (1L << 24)) { bail = 1; break; }
            }
        }
        __syncthreads();
        __builtin_amdgcn_fence(__ATOMIC_ACQUIRE, "workgroup"); // no buffer_inv
        __asm__ __volatile__("" ::: "memory");

        // ---- h-part: burst-issue all 32 A-frag loads (write-once slot t),
        // then next step's e-loads behind them; MFMAs consume in load order
        const f16* Ah = h16 + ((size_t)t * 64 + b) * Hn + ko;
        f16x8 ha[32];
        #pragma unroll
        for (int ks = 0; ks < 32; ++ks)
            ha[ks] = *(const f16x8*)&Ah[ks * 32];

        {
            int tn = (t + 1) & 511;   // harmless wrap on last iter
            const f16* Aen = e16 + ((size_t)tn * 64 + b) * En + ko;
            #pragma unroll
            for (int ks = 0; ks < 16; ++ks)
                ea[ks] = *(const f16x8*)&Aen[ks * 32];
        }

        f32x4 acc = accE;   // C-in chaining
        #pragma unroll
        for (int ks = 0; ks < 32; ++ks) {
            f16x8 bh = *(const f16x8*)&Wsh_r[ks * 512];
            acc = __builtin_amdgcn_mfma_f32_16x16x32_f16(ha[ks], bh, acc, 0, 0, 0);
        }

        // ---- cell update. D: col=cl (gate jcol), row=q*4+r (batch w*16+q*4+r)
        #pragma unroll
        for (int r = 0; r < 4; ++r) {
            float av = acc[r];
            float iv = __shfl(av, (lane & 48) | co,      64);
            float fv = __shfl(av, (lane & 48) | 4 | co,  64);
            float gv = __shfl(av, (lane & 48) | 8 | co,  64);
            float ov = __shfl(av, (lane & 48) | 12 | co, 64);
            if (cl < 4) {
                float i_ = fsig(iv);
                float f_ = fsig(fv);
                float g_ = ftanh(gv);
                float o_ = fsig(ov);
                float cn = f_ * cst[r] + i_ * g_;
                cst[r] = cn;
                float hn = o_ * ftanh(cn);
                unsigned my = (unsigned)__builtin_bit_cast(unsigned short, (f16)hn);
                // pair-pack with neighbor lane (cl pairs (0,1),(2,3) both
                // inside the cl<4 region -> all shfl participants active)
                unsigned nb = __shfl(my, lane ^ 1, 64);
                if ((co & 1) == 0) {
                    unsigned pk = my | (nb << 16);   // dims (d0+co, d0+co+1)
                    int br = w * 16 + q * 4 + r;
                    unsigned* dst = (unsigned*)&h16[((size_t)(t + 1) * 64 + br) * Hn + d0 + co];
                    // to coherence point (sc0 sc1), bypasses L2 -> L2 clean
                    __hip_atomic_store(dst, pk, __ATOMIC_RELAXED,
                                       __HIP_MEMORY_SCOPE_AGENT);
                }
            }
        }

        // ---- arrive: __syncthreads drains vmcnt(0) per wave (stores acked)
        __syncthreads();
        __asm__ __volatile__("" ::: "memory");
        if (tid == 0) {
            unsigned prev = __hip_atomic_fetch_add(grp, 1u, __ATOMIC_RELAXED,
                                                   __HIP_MEMORY_SCOPE_AGENT);
            if ((prev & 15u) == 15u)   // 16th arrival of this step in group
                __hip_atomic_fetch_add(root, 1u, __ATOMIC_RELAXED,
                                       __HIP_MEMORY_SCOPE_AGENT);
        }
    }
}

// ---------------------------------------------------------------- energy GEMM
// rows r = t*64+b (h16 linear row r+64); energy[r] += tanh(row.Wa[d]) * va[d]
__global__ __launch_bounds__(256) void energy_k(
    const f16* __restrict__ h16,        // [513*64][1024] f16
    const f16* __restrict__ Wa_hi,      // [H][H]
    const float* __restrict__ va,       // [H]
    float* __restrict__ energy)         // [B*S] (r-indexed), pre-zeroed
{
    __shared__ f16 Was[128][136];
    const int bid = blockIdx.x;
    const int rb = bid >> 3;
    const int nb = bid & 7;
    const int tid = threadIdx.x;
    const int lane = tid & 63, w = tid >> 6, cl = lane & 15, q = lane >> 4;
    const int r0 = rb * 64 + w * 16 + cl;

    f32x4 acc[8];
    #pragma unroll
    for (int i = 0; i < 8; ++i) acc[i] = (f32x4){0.f, 0.f, 0.f, 0.f};

    for (int kc = 0; kc < 8; ++kc) {
        __syncthreads();
        for (int i = tid; i < 128 * 16; i += 256) {
            int dd = i >> 4;
            int kv = (i & 15) * 8;
            *(f16x8*)&Was[dd][kv] =
                *(const f16x8*)&Wa_hi[(size_t)(nb * 128 + dd) * Hn + kc * 128 + kv];
        }
        __syncthreads();
        const f16* A = h16 + (size_t)(r0 + 64) * Hn + kc * 128;
        #pragma unroll
        for (int ks = 0; ks < 4; ++ks) {
            f16x8 ah = *(const f16x8*)&A[ks * 32 + q * 8];
            #pragma unroll
            for (int nt = 0; nt < 8; ++nt) {
                f16x8 bb = *(const f16x8*)&Was[nt * 16 + cl][ks * 32 + q * 8];
                acc[nt] = __builtin_amdgcn_mfma_f32_16x16x32_f16(ah, bb, acc[nt], 0, 0, 0);
            }
        }
    }

    float rowsum[4] = {0.f, 0.f, 0.f, 0.f};
    #pragma unroll
    for (int nt = 0; nt < 8; ++nt) {
        float vv = va[nb * 128 + nt * 16 + cl];
        #pragma unroll
        for (int r = 0; r < 4; ++r)
            rowsum[r] += tanhf(acc[nt][r]) * vv;
    }
    #pragma unroll
    for (int m = 1; m < 16; m <<= 1)
        #pragma unroll
        for (int r = 0; r < 4; ++r)
            rowsum[r] += __shfl_xor(rowsum[r], m, 64);
    if (cl == 0) {
        #pragma unroll
        for (int r = 0; r < 4; ++r)
            atomicAdd(&energy[(size_t)rb * 64 + w * 16 + q * 4 + r], rowsum[r]);
    }
}

// ------------------------------------------------- masked softmax + context
// energy index for (b,s) = s*64 + b
__global__ __launch_bounds__(256) void softctx_k(
    const float* __restrict__ energy, const int* __restrict__ x,
    const f16* __restrict__ h16,
    float* __restrict__ context)   // [B][H]
{
    __shared__ float sm[512];
    __shared__ float red[256];
    const int b = blockIdx.x, tid = threadIdx.x;
    const int s0 = tid, s1 = tid + 256;
    float e0 = (x[b * Sn + s0] != 0) ? energy[s0 * 64 + b] : -1e10f;
    float e1 = (x[b * Sn + s1] != 0) ? energy[s1 * 64 + b] : -1e10f;
    red[tid] = fmaxf(e0, e1);
    __syncthreads();
    for (int st = 128; st > 0; st >>= 1) {
        if (tid < st) red[tid] = fmaxf(red[tid], red[tid + st]);
        __syncthreads();
    }
    float M = red[0];
    __syncthreads();
    float p0 = expf(e0 - M), p1 = expf(e1 - M);
    red[tid] = p0 + p1;
    __syncthreads();
    for (int st = 128; st > 0; st >>= 1) {
        if (tid < st) red[tid] += red[tid + st];
        __syncthreads();
    }
    float inv = 1.f / red[0];
    sm[s0] = p0 * inv; sm[s1] = p1 * inv;
    __syncthreads();

    const int d0v = tid * 4;
    float a0 = 0.f, a1 = 0.f, a2 = 0.f, a3 = 0.f;
    for (int s = 0; s < Sn; ++s) {
        float at = sm[s];
        f16x4 hv = *(const f16x4*)&h16[((size_t)(s + 1) * 64 + b) * Hn + d0v];
        a0 += at * (float)hv[0];
        a1 += at * (float)hv[1];
        a2 += at * (float)hv[2];
        a3 += at * (float)hv[3];
    }
    float* cp = context + (size_t)b * Hn + d0v;
    cp[0] = a0; cp[1] = a1; cp[2] = a2; cp[3] = a3;
}

// ---------------------------------------------------------------- logits
__global__ __launch_bounds__(256) void logits_k(
    const float* __restrict__ context, const float* __restrict__ WV,
    const float* __restrict__ bV, float* __restrict__ out)
{
    __shared__ float red[10][257];
    const int b = blockIdx.x, tid = threadIdx.x;
    const int d0v = tid * 4;
    float4 cv = *(const float4*)&context[(size_t)b * Hn + d0v];
    #pragma unroll
    for (int cls = 0; cls < 10; ++cls) {
        float4 wv = *(const float4*)&WV[cls * Hn + d0v];
        red[cls][tid] = cv.x * wv.x + cv.y * wv.y + cv.z * wv.z + cv.w * wv.w;
    }
    __syncthreads();
    for (int st = 128; st > 0; st >>= 1) {
        if (tid < st)
            #pragma unroll
            for (int cls = 0; cls < 10; ++cls)
                red[cls][tid] += red[cls][tid + st];
        __syncthreads();
    }
    if (tid < 10) out[b * 10 + tid] = red[tid][0] + bV[tid];
}

// ---------------------------------------------------------------- launch
extern "C" void kernel_launch(void* const* d_in, const int* in_sizes, int n_in,
                              void* d_out, int out_size, void* d_ws, size_t ws_size,
                              hipStream_t stream)
{
    const int*   x   = (const int*)d_in[0];
    const float* emb = (const float*)d_in[1];
    const float* Wg  = (const float*)d_in[2];
    const float* bg  = (const float*)d_in[3];
    const float* Wa  = (const float*)d_in[4];
    const float* va  = (const float*)d_in[5];
    const float* WV  = (const float*)d_in[6];
    const float* bV  = (const float*)d_in[7];
    float* out = (float*)d_out;

    char* ws = (char*)d_ws;
    size_t o = 0;
    auto alloc = [&](size_t bytes) { void* p = ws + o; o += (bytes + 255) & ~(size_t)255; return p; };
    f16*      e16   = (f16*)alloc((size_t)Sn * Bn * En * 2);        // 33.5 MB
    f16*      Wa_hi = (f16*)alloc((size_t)Hn * Hn * 2);             // 2 MB
    f16*      h16   = (f16*)alloc((size_t)(Sn + 1) * Bn * Hn * 2);  // 67.2 MB
    float*    energy= (float*)alloc((size_t)Bn * Sn * 4);
    float*    ctx   = (float*)alloc((size_t)Bn * Hn * 4);
    unsigned* bar   = (unsigned*)alloc(4096);
    // total ~103 MB

    hipMemsetAsync(h16, 0, (size_t)Bn * Hn * 2, stream);    // slot 0 = zeros
    hipMemsetAsync(energy, 0, (size_t)Bn * Sn * 4, stream);
    hipMemsetAsync(bar, 0, 4096, stream);

    gather_e_k<<<8192, 256, 0, stream>>>(x, emb, e16);
    split_wa_k<<<512, 256, 0, stream>>>(Wa, Wa_hi);

    lstm_persist_k<<<256, 256, 0, stream>>>(e16, Wg, bg, h16, bar);

    energy_k<<<512 * 8, 256, 0, stream>>>(h16, Wa_hi, va, energy);
    softctx_k<<<Bn, 256, 0, stream>>>(energy, x, h16, ctx);
    logits_k<<<Bn, 256, 0, stream>>>(ctx, WV, bV, out);
}

// Round 12
// 3798.715 us; speedup vs baseline: 1.0444x; 1.0444x over previous
//
#include <hip/hip_runtime.h>

// LSTM_36807869726767 — round 16: FORCED h-load burst via inline-asm +
// counted vmcnt streaming consume.
// Round-15 null: launch_bounds(256,1) didn't move VGPR (68) — the pressure-
// aware scheduler rolls static arrays back into a narrow load->use window
// regardless of the occupancy ceiling. Latency theory still untested; per
// pre-commit, go to manual vmcnt control (AITER pattern):
//  - 32 x global_load_dwordx4 inline asm ("memory" clobber: nothing crosses;
//    asm outputs are unelidable -> allocator MUST hold 128 VGPRs).
//  - consume with tie-operand waits: asm("s_waitcnt vmcnt(31-ks)":"+v"(ha[ks]))
//    -> each MFMA data-depends on its own wait (rule-#18-proof). Constants
//    safe: any tracked load drifting into the region issued AFTER all 32 ha
//    asms -> vmcnt(31-ks) only ever stronger.
//  - e-prefetch moved after h-consume (normal tracked loads; latency hides
//    under cell update + stores + barrier + next spin).
// Tell: VGPR >= 200. Flat dur with high VGPR -> latency theory falsified,
// next round attacks the publish/barrier chain.
// B=64, S=512, E=512, H=1024, NCLS=10, PAD=0. All float I/O f32.

typedef _Float16 f16;
typedef __attribute__((ext_vector_type(8))) _Float16 f16x8;
typedef __attribute__((ext_vector_type(4))) _Float16 f16x4;
typedef __attribute__((ext_vector_type(4))) float f32x4;

#define Bn 64
#define Sn 512
#define En 512
#define Hn 1024

__device__ __forceinline__ float fsig(float x) {
    return __builtin_amdgcn_rcpf(1.f + __expf(-x));
}
__device__ __forceinline__ float ftanh(float x) {
    return 2.f * __builtin_amdgcn_rcpf(1.f + __expf(-2.f * x)) - 1.f;
}

// ------------------------------------------------- gather e -> f16 [t][b][k]
__global__ __launch_bounds__(256) void gather_e_k(
    const int* __restrict__ x, const float* __restrict__ emb,
    f16* __restrict__ e16)
{
    size_t g = (size_t)blockIdx.x * 256 + threadIdx.x;
    int row = (int)(g >> 6);          // t*64 + b
    int ko  = (int)(g & 63) * 8;
    int t = row >> 6, b = row & 63;
    int tok = x[b * Sn + t];
    float4 a  = *(const float4*)&emb[(size_t)tok * En + ko];
    float4 a2 = *(const float4*)&emb[(size_t)tok * En + ko + 4];
    float v[8] = {a.x, a.y, a.z, a.w, a2.x, a2.y, a2.z, a2.w};
    f16x8 h;
    #pragma unroll
    for (int i = 0; i < 8; ++i) h[i] = (f16)v[i];
    *(f16x8*)&e16[(size_t)row * En + ko] = h;
}

// ------------------------------------------------------------- Wa f32 -> f16
__global__ __launch_bounds__(256) void split_wa_k(
    const float* __restrict__ Wa, f16* __restrict__ hi)
{
    size_t g = ((size_t)blockIdx.x * 256 + threadIdx.x) * 8;
    float4 a = *(const float4*)&Wa[g];
    float4 b = *(const float4*)&Wa[g + 4];
    float v[8] = {a.x, a.y, a.z, a.w, b.x, b.y, b.z, b.w};
    f16x8 h;
    #pragma unroll
    for (int i = 0; i < 8; ++i) h[i] = (f16)v[i];
    *(f16x8*)&hi[g] = h;
}

// ------------------------------------------- persistent LSTM recurrence
// 256 blocks x 256 thr (1 wave/SIMD, all CUs). Block bk owns h-dims
// d0=4*bk..d0+3 (16 gate rows). Wave w = 16 batch rows. h state: write-once
// slots h16[slot][b][k] f16; slot t = state entering step t; slot 0 zeroed;
// step t writes slot t+1 via relaxed agent-scope u32 stores (two f16 packed;
// write-through to coherence point; readers use normal cached loads of
// write-once lines -> no stale data, no fences needed).
// Barrier: round-8 block-level (tid0 polls root, __syncthreads, tid0 arrive).
__global__ __launch_bounds__(256, 1) void lstm_persist_k(
    const f16* __restrict__ e16,      // [512*64][512]
    const float* __restrict__ Wg,     // [4096][1536] f32
    const float* __restrict__ bg,     // [4096]
    f16* __restrict__ h16,            // [513][64][1024] f16
    unsigned* __restrict__ bar)       // [16*32] group counters + [512] root
{
    // k-major [kchunk][16 rows][8]: zero pad, conflict-free ds_read_b128
    __shared__ f16 Wse[64 * 16 * 8];    // 16 KB (e-part, k=0..511)
    __shared__ f16 Wsh[128 * 16 * 8];   // 32 KB (h-part, k=512..1535)

    const int tid = threadIdx.x;
    const int bk  = blockIdx.x;     // 0..255
    const int d0  = bk * 4;

    // ---- one-time: stage 16 weight rows (f32 -> f16), k-major
    {
        int n = tid >> 4, l16 = tid & 15;
        int j = (n >> 2) * 1024 + d0 + (n & 3);
        const float* src = Wg + (size_t)j * 1536;
        for (int k = l16 * 4; k < 1536; k += 64) {
            float4 v = *(const float4*)&src[k];
            float vv[4] = {v.x, v.y, v.z, v.w};
            #pragma unroll
            for (int i = 0; i < 4; ++i) {
                int kk = k + i;
                f16 hv = (f16)vv[i];
                if (kk < 512) {
                    Wse[((kk >> 3) * 16 + n) * 8 + (kk & 7)] = hv;
                } else {
                    int kh = kk - 512;
                    Wsh[((kh >> 3) * 16 + n) * 8 + (kh & 7)] = hv;
                }
            }
        }
    }
    __syncthreads();

    const int lane = tid & 63;
    const int w    = tid >> 6;
    const int cl   = lane & 15;
    const int q    = lane >> 4;
    const int b    = w * 16 + cl;
    const int ko   = q * 8;
    const int co   = cl & 3;
    const int jcol = (cl >> 2) * 1024 + d0 + (cl & 3);
    const float bgv = bg[jcol];

    const int wbase = (q * 16 + cl) * 8;   // lane base into k-major LDS
    const f16* Wse_r = &Wse[wbase];
    const f16* Wsh_r = &Wsh[wbase];

    unsigned* grp  = &bar[(bk >> 4) * 32];
    unsigned* root = &bar[512];

    float cst[4] = {0.f, 0.f, 0.f, 0.f};
    int bail = 0;

    // ---- e software pipeline: prime ea with step 0's fragments
    f16x8 ea[16];
    {
        const f16* Ae0 = e16 + (size_t)b * En + ko;
        #pragma unroll
        for (int ks = 0; ks < 16; ++ks)
            ea[ks] = *(const f16x8*)&Ae0[ks * 32];
    }

    for (int t = 0; t < Sn; ++t) {
        // ---- e-part MFMAs from registers loaded one step ago
        f32x4 accE = {bgv, bgv, bgv, bgv};   // bias folded in
        #pragma unroll
        for (int ks = 0; ks < 16; ++ks) {
            f16x8 bb = *(const f16x8*)&Wse_r[ks * 512];
            accE = __builtin_amdgcn_mfma_f32_16x16x32_f16(ea[ks], bb, accE, 0, 0, 0);
        }

        // ---- wait for step t-1 (root >= 16*t); relaxed spin, no acquire
        if (tid == 0 && t > 0 && !bail) {
            unsigned tgt = 16u * (unsigned)t;
            long spins = 0;
            while (__hip_atomic_load(root, __ATOMIC_RELAXED,
                                     __HIP_MEMORY_SCOPE_AGENT) < tgt) {
                __builtin_amdgcn_s_sleep(1);
                if (++spins > (1L << 24)) { bail = 1; break; }
            }
        }
        __syncthreads();
        __builtin_amdgcn_fence(__ATOMIC_ACQUIRE, "workgroup"); // no buffer_inv
        __asm__ __volatile__("" ::: "memory");

        // ---- h-part: FORCED burst — 32 asm loads issued back-to-back
        // (write-once slot t; plain global_load, same inst as compiler's)
        const f16* Ah = h16 + ((size_t)t * 64 + b) * Hn + ko;
        f16x8 ha[32];
        #pragma unroll
        for (int ks = 0; ks < 32; ++ks)
            asm volatile("global_load_dwordx4 %0, %1, off offset:%2"
                         : "=v"(ha[ks])
                         : "v"(Ah), "i"(ks * 64)
                         : "memory");

        // ---- streaming consume: counted waits (loads complete in issue
        // order; tie-operand makes each MFMA depend on its own wait)
        f32x4 acc = accE;   // C-in chaining
        #pragma unroll
        for (int ks = 0; ks < 32; ++ks) {
            asm volatile("s_waitcnt vmcnt(%1)"
                         : "+v"(ha[ks]) : "i"(31 - ks));
            f16x8 bh = *(const f16x8*)&Wsh_r[ks * 512];
            acc = __builtin_amdgcn_mfma_f32_16x16x32_f16(ha[ks], bh, acc, 0, 0, 0);
        }

        // ---- next step's e-prefetch (normal tracked loads; latency hides
        // under cell update + stores + barrier + next spin)
        {
            int tn = (t + 1) & 511;   // harmless wrap on last iter
            const f16* Aen = e16 + ((size_t)tn * 64 + b) * En + ko;
            #pragma unroll
            for (int ks = 0; ks < 16; ++ks)
                ea[ks] = *(const f16x8*)&Aen[ks * 32];
        }

        // ---- cell update. D: col=cl (gate jcol), row=q*4+r (batch w*16+q*4+r)
        #pragma unroll
        for (int r = 0; r < 4; ++r) {
            float av = acc[r];
            float iv = __shfl(av, (lane & 48) | co,      64);
            float fv = __shfl(av, (lane & 48) | 4 | co,  64);
            float gv = __shfl(av, (lane & 48) | 8 | co,  64);
            float ov = __shfl(av, (lane & 48) | 12 | co, 64);
            if (cl < 4) {
                float i_ = fsig(iv);
                float f_ = fsig(fv);
                float g_ = ftanh(gv);
                float o_ = fsig(ov);
                float cn = f_ * cst[r] + i_ * g_;
                cst[r] = cn;
                float hn = o_ * ftanh(cn);
                unsigned my = (unsigned)__builtin_bit_cast(unsigned short, (f16)hn);
                // pair-pack with neighbor lane (cl pairs (0,1),(2,3) both
                // inside the cl<4 region -> all shfl participants active)
                unsigned nb = __shfl(my, lane ^ 1, 64);
                if ((co & 1) == 0) {
                    unsigned pk = my | (nb << 16);   // dims (d0+co, d0+co+1)
                    int br = w * 16 + q * 4 + r;
                    unsigned* dst = (unsigned*)&h16[((size_t)(t + 1) * 64 + br) * Hn + d0 + co];
                    // to coherence point (sc0 sc1), bypasses L2 -> L2 clean
                    __hip_atomic_store(dst, pk, __ATOMIC_RELAXED,
                                       __HIP_MEMORY_SCOPE_AGENT);
                }
            }
        }

        // ---- arrive: __syncthreads drains vmcnt(0) per wave (stores acked)
        __syncthreads();
        __asm__ __volatile__("" ::: "memory");
        if (tid == 0) {
            unsigned prev = __hip_atomic_fetch_add(grp, 1u, __ATOMIC_RELAXED,
                                                   __HIP_MEMORY_SCOPE_AGENT);
            if ((prev & 15u) == 15u)   // 16th arrival of this step in group
                __hip_atomic_fetch_add(root, 1u, __ATOMIC_RELAXED,
                                       __HIP_MEMORY_SCOPE_AGENT);
        }
    }
}

// ---------------------------------------------------------------- energy GEMM
// rows r = t*64+b (h16 linear row r+64); energy[r] += tanh(row.Wa[d]) * va[d]
__global__ __launch_bounds__(256) void energy_k(
    const f16* __restrict__ h16,        // [513*64][1024] f16
    const f16* __restrict__ Wa_hi,      // [H][H]
    const float* __restrict__ va,       // [H]
    float* __restrict__ energy)         // [B*S] (r-indexed), pre-zeroed
{
    __shared__ f16 Was[128][136];
    const int bid = blockIdx.x;
    const int rb = bid >> 3;
    const int nb = bid & 7;
    const int tid = threadIdx.x;
    const int lane = tid & 63, w = tid >> 6, cl = lane & 15, q = lane >> 4;
    const int r0 = rb * 64 + w * 16 + cl;

    f32x4 acc[8];
    #pragma unroll
    for (int i = 0; i < 8; ++i) acc[i] = (f32x4){0.f, 0.f, 0.f, 0.f};

    for (int kc = 0; kc < 8; ++kc) {
        __syncthreads();
        for (int i = tid; i < 128 * 16; i += 256) {
            int dd = i >> 4;
            int kv = (i & 15) * 8;
            *(f16x8*)&Was[dd][kv] =
                *(const f16x8*)&Wa_hi[(size_t)(nb * 128 + dd) * Hn + kc * 128 + kv];
        }
        __syncthreads();
        const f16* A = h16 + (size_t)(r0 + 64) * Hn + kc * 128;
        #pragma unroll
        for (int ks = 0; ks < 4; ++ks) {
            f16x8 ah = *(const f16x8*)&A[ks * 32 + q * 8];
            #pragma unroll
            for (int nt = 0; nt < 8; ++nt) {
                f16x8 bb = *(const f16x8*)&Was[nt * 16 + cl][ks * 32 + q * 8];
                acc[nt] = __builtin_amdgcn_mfma_f32_16x16x32_f16(ah, bb, acc[nt], 0, 0, 0);
            }
        }
    }

    float rowsum[4] = {0.f, 0.f, 0.f, 0.f};
    #pragma unroll
    for (int nt = 0; nt < 8; ++nt) {
        float vv = va[nb * 128 + nt * 16 + cl];
        #pragma unroll
        for (int r = 0; r < 4; ++r)
            rowsum[r] += tanhf(acc[nt][r]) * vv;
    }
    #pragma unroll
    for (int m = 1; m < 16; m <<= 1)
        #pragma unroll
        for (int r = 0; r < 4; ++r)
            rowsum[r] += __shfl_xor(rowsum[r], m, 64);
    if (cl == 0) {
        #pragma unroll
        for (int r = 0; r < 4; ++r)
            atomicAdd(&energy[(size_t)rb * 64 + w * 16 + q * 4 + r], rowsum[r]);
    }
}

// ------------------------------------------------- masked softmax + context
// energy index for (b,s) = s*64 + b
__global__ __launch_bounds__(256) void softctx_k(
    const float* __restrict__ energy, const int* __restrict__ x,
    const f16* __restrict__ h16,
    float* __restrict__ context)   // [B][H]
{
    __shared__ float sm[512];
    __shared__ float red[256];
    const int b = blockIdx.x, tid = threadIdx.x;
    const int s0 = tid, s1 = tid + 256;
    float e0 = (x[b * Sn + s0] != 0) ? energy[s0 * 64 + b] : -1e10f;
    float e1 = (x[b * Sn + s1] != 0) ? energy[s1 * 64 + b] : -1e10f;
    red[tid] = fmaxf(e0, e1);
    __syncthreads();
    for (int st = 128; st > 0; st >>= 1) {
        if (tid < st) red[tid] = fmaxf(red[tid], red[tid + st]);
        __syncthreads();
    }
    float M = red[0];
    __syncthreads();
    float p0 = expf(e0 - M), p1 = expf(e1 - M);
    red[tid] = p0 + p1;
    __syncthreads();
    for (int st = 128; st > 0; st >>= 1) {
        if (tid < st) red[tid] += red[tid + st];
        __syncthreads();
    }
    float inv = 1.f / red[0];
    sm[s0] = p0 * inv; sm[s1] = p1 * inv;
    __syncthreads();

    const int d0v = tid * 4;
    float a0 = 0.f, a1 = 0.f, a2 = 0.f, a3 = 0.f;
    for (int s = 0; s < Sn; ++s) {
        float at = sm[s];
        f16x4 hv = *(const f16x4*)&h16[((size_t)(s + 1) * 64 + b) * Hn + d0v];
        a0 += at * (float)hv[0];
        a1 += at * (float)hv[1];
        a2 += at * (float)hv[2];
        a3 += at * (float)hv[3];
    }
    float* cp = context + (size_t)b * Hn + d0v;
    cp[0] = a0; cp[1] = a1; cp[2] = a2; cp[3] = a3;
}

// ---------------------------------------------------------------- logits
__global__ __launch_bounds__(256) void logits_k(
    const float* __restrict__ context, const float* __restrict__ WV,
    const float* __restrict__ bV, float* __restrict__ out)
{
    __shared__ float red[10][257];
    const int b = blockIdx.x, tid = threadIdx.x;
    const int d0v = tid * 4;
    float4 cv = *(const float4*)&context[(size_t)b * Hn + d0v];
    #pragma unroll
    for (int cls = 0; cls < 10; ++cls) {
        float4 wv = *(const float4*)&WV[cls * Hn + d0v];
        red[cls][tid] = cv.x * wv.x + cv.y * wv.y + cv.z * wv.z + cv.w * wv.w;
    }
    __syncthreads();
    for (int st = 128; st > 0; st >>= 1) {
        if (tid < st)
            #pragma unroll
            for (int cls = 0; cls < 10; ++cls)
                red[cls][tid] += red[cls][tid + st];
        __syncthreads();
    }
    if (tid < 10) out[b * 10 + tid] = red[tid][0] + bV[tid];
}

// ---------------------------------------------------------------- launch
extern "C" void kernel_launch(void* const* d_in, const int* in_sizes, int n_in,
                              void* d_out, int out_size, void* d_ws, size_t ws_size,
                              hipStream_t stream)
{
    const int*   x   = (const int*)d_in[0];
    const float* emb = (const float*)d_in[1];
    const float* Wg  = (const float*)d_in[2];
    const float* bg  = (const float*)d_in[3];
    const float* Wa  = (const float*)d_in[4];
    const float* va  = (const float*)d_in[5];
    const float* WV  = (const float*)d_in[6];
    const float* bV  = (const float*)d_in[7];
    float* out = (float*)d_out;

    char* ws = (char*)d_ws;
    size_t o = 0;
    auto alloc = [&](size_t bytes) { void* p = ws + o; o += (bytes + 255) & ~(size_t)255; return p; };
    f16*      e16   = (f16*)alloc((size_t)Sn * Bn * En * 2);        // 33.5 MB
    f16*      Wa_hi = (f16*)alloc((size_t)Hn * Hn * 2);             // 2 MB
    f16*      h16   = (f16*)alloc((size_t)(Sn + 1) * Bn * Hn * 2);  // 67.2 MB
    float*    energy= (float*)alloc((size_t)Bn * Sn * 4);
    float*    ctx   = (float*)alloc((size_t)Bn * Hn * 4);
    unsigned* bar   = (unsigned*)alloc(4096);
    // total ~103 MB

    hipMemsetAsync(h16, 0, (size_t)Bn * Hn * 2, stream);    // slot 0 = zeros
    hipMemsetAsync(energy, 0, (size_t)Bn * Sn * 4, stream);
    hipMemsetAsync(bar, 0, 4096, stream);

    gather_e_k<<<8192, 256, 0, stream>>>(x, emb, e16);
    split_wa_k<<<512, 256, 0, stream>>>(Wa, Wa_hi);

    lstm_persist_k<<<256, 256, 0, stream>>>(e16, Wg, bg, h16, bar);

    energy_k<<<512 * 8, 256, 0, stream>>>(h16, Wa_hi, va, energy);
    softctx_k<<<Bn, 256, 0, stream>>>(energy, x, h16, ctx);
    logits_k<<<Bn, 256, 0, stream>>>(ctx, WV, bV, out);
}